// Round 1
// baseline (371.677 us; speedup 1.0000x reference)
//
#include <hip/hip_runtime.h>
#include <math.h>

#define TT 32
#define EPSF 1e-9f

constexpr int BLOCK = 256;
constexpr int GRID  = 2048;   // 2048 blocks * 32 rows/block-iter = 65536 rows/iter; 32 iters at N=2M

// Kernel 1: per-block partial sums of (loss * sw) and (sw), written as double2 per block.
__global__ __launch_bounds__(BLOCK) void nll_partial(
    const float* __restrict__ preds,
    const int*   __restrict__ targets,
    const float* __restrict__ weight,
    const float* __restrict__ sample_weight,
    double*      __restrict__ partials,   // [gridDim.x * 2]
    int N)
{
    __shared__ float w_sh[TT];
    __shared__ float wcm_sh[TT];
    __shared__ double red_l[BLOCK / 64];
    __shared__ double red_s[BLOCK / 64];

    const int tid = threadIdx.x;

    // Precompute weight and cumulative-mean weight (T=32, trivial O(T^2) once per block)
    if (tid < TT) {
        w_sh[tid] = weight[tid];
    }
    __syncthreads();
    if (tid < TT) {
        float s = 0.f;
        for (int t = 0; t <= tid; ++t) s += w_sh[t];
        wcm_sh[tid] = s / (float)(tid + 1);
    }
    __syncthreads();

    const int lane = tid & 63;
    const int j    = lane & 7;                 // lane within 8-lane row group
    const int base = 4 * j;                    // first element index this lane owns

    long long g       = (long long)blockIdx.x * (BLOCK / 8) + (tid >> 3);
    const long long ngroups = (long long)GRID * (BLOCK / 8);

    float acc_loss = 0.f;  // only j==0 lanes accumulate
    float acc_sw   = 0.f;

    const float4* preds4   = (const float4*)preds;
    const int2*   targets2 = (const int2*)targets;

    for (long long row = g; row < (long long)N; row += ngroups) {
        // Coalesced: 8 lanes * float4 = one 128B row; wave = 8 consecutive rows = 1 KB contiguous
        float4 x4 = preds4[row * (TT / 4) + j];

        // row max (stable softmax)
        float m = fmaxf(fmaxf(x4.x, x4.y), fmaxf(x4.z, x4.w));
        m = fmaxf(m, __shfl_xor(m, 1));
        m = fmaxf(m, __shfl_xor(m, 2));
        m = fmaxf(m, __shfl_xor(m, 4));

        float e0 = __expf(x4.x - m);
        float e1 = __expf(x4.y - m);
        float e2 = __expf(x4.z - m);
        float e3 = __expf(x4.w - m);
        float z = e0 + e1 + e2 + e3;
        z += __shfl_xor(z, 1);
        z += __shfl_xor(z, 2);
        z += __shfl_xor(z, 4);
        float inv = __frcp_rn(z);

        // clipped pmf (clip BEFORE cumsum, matching reference)
        float p0 = fminf(fmaxf(e0 * inv, EPSF), 1.0f - EPSF);
        float p1 = fminf(fmaxf(e1 * inv, EPSF), 1.0f - EPSF);
        float p2 = fminf(fmaxf(e2 * inv, EPSF), 1.0f - EPSF);
        float p3 = fminf(fmaxf(e3 * inv, EPSF), 1.0f - EPSF);

        // targets: all 8 lanes of a group load the same int2 (same cache line, no extra HBM)
        int2 t2 = targets2[row];
        int d = t2.x < 0 ? 0 : (t2.x > TT - 1 ? TT - 1 : t2.x);

        // p_d and cdf[d] partials
        float pd_part  = 0.f;
        float cdf_part = 0.f;
        pd_part  += (base + 0 == d) ? p0 : 0.f;
        pd_part  += (base + 1 == d) ? p1 : 0.f;
        pd_part  += (base + 2 == d) ? p2 : 0.f;
        pd_part  += (base + 3 == d) ? p3 : 0.f;
        cdf_part += (base + 0 <= d) ? p0 : 0.f;
        cdf_part += (base + 1 <= d) ? p1 : 0.f;
        cdf_part += (base + 2 <= d) ? p2 : 0.f;
        cdf_part += (base + 3 <= d) ? p3 : 0.f;
        pd_part  += __shfl_xor(pd_part, 1);
        cdf_part += __shfl_xor(cdf_part, 1);
        pd_part  += __shfl_xor(pd_part, 2);
        cdf_part += __shfl_xor(cdf_part, 2);
        pd_part  += __shfl_xor(pd_part, 4);
        cdf_part += __shfl_xor(cdf_part, 4);

        if (j == 0) {
            float sw = sample_weight[row];
            float Sd = 1.0f - cdf_part;
            Sd = fminf(fmaxf(Sd, EPSF), 1.0f);
            float loss;
            if (t2.y != 0) {
                loss = -__logf(pd_part) * w_sh[d];
            } else {
                loss = -__logf(Sd) * wcm_sh[d];
            }
            acc_loss += loss * sw;
            acc_sw   += sw;
        }
    }

    // Reduce across the block: wave butterfly (j!=0 lanes contribute 0), then LDS across waves
    double dl = (double)acc_loss;
    double ds = (double)acc_sw;
    for (int mask = 1; mask < 64; mask <<= 1) {
        dl += __shfl_xor(dl, mask);
        ds += __shfl_xor(ds, mask);
    }
    const int w = tid >> 6;
    if (lane == 0) { red_l[w] = dl; red_s[w] = ds; }
    __syncthreads();
    if (tid == 0) {
        double L = 0.0, S = 0.0;
        for (int i = 0; i < BLOCK / 64; ++i) { L += red_l[i]; S += red_s[i]; }
        partials[2 * (long long)blockIdx.x + 0] = L;
        partials[2 * (long long)blockIdx.x + 1] = S;
    }
}

// Kernel 2: reduce per-block partials, finalize scalar.
__global__ __launch_bounds__(256) void nll_final(
    const double* __restrict__ partials, int nblocks, float* __restrict__ out)
{
    const int tid = threadIdx.x;
    double sl = 0.0, ss = 0.0;
    for (int i = tid; i < nblocks; i += 256) {
        sl += partials[2 * i + 0];
        ss += partials[2 * i + 1];
    }
    for (int mask = 1; mask < 64; mask <<= 1) {
        sl += __shfl_xor(sl, mask);
        ss += __shfl_xor(ss, mask);
    }
    __shared__ double s_l[4], s_s[4];
    const int w = tid >> 6;
    if ((tid & 63) == 0) { s_l[w] = sl; s_s[w] = ss; }
    __syncthreads();
    if (tid == 0) {
        double L = 0.0, S = 0.0;
        for (int i = 0; i < 4; ++i) { L += s_l[i]; S += s_s[i]; }
        double denom = S > 1e-9 ? S : 1e-9;
        out[0] = (float)(L / denom);
    }
}

extern "C" void kernel_launch(void* const* d_in, const int* in_sizes, int n_in,
                              void* d_out, int out_size, void* d_ws, size_t ws_size,
                              hipStream_t stream) {
    const float* preds         = (const float*)d_in[0];
    const int*   targets       = (const int*)d_in[1];
    const float* weight        = (const float*)d_in[2];
    const float* sample_weight = (const float*)d_in[3];
    float*       out           = (float*)d_out;
    double*      partials      = (double*)d_ws;

    const int N = in_sizes[3];   // sample_weight has N elements

    int grid = GRID;
    size_t need = (size_t)grid * 2 * sizeof(double);
    if (ws_size < need) {
        grid = (int)(ws_size / (2 * sizeof(double)));
        if (grid < 1) grid = 1;
    }

    nll_partial<<<grid, BLOCK, 0, stream>>>(preds, targets, weight, sample_weight, partials, N);
    nll_final<<<1, 256, 0, stream>>>(partials, grid, out);
}